// Round 4
// baseline (1194.878 us; speedup 1.0000x reference)
//
#include <hip/hip_runtime.h>

typedef unsigned short u16;
typedef unsigned int u32;
typedef __attribute__((ext_vector_type(8))) short short8;
typedef __attribute__((ext_vector_type(8))) _Float16 half8;
typedef __attribute__((ext_vector_type(2))) __fp16 fp16x2;
typedef __attribute__((ext_vector_type(4))) float f32x4;
typedef __attribute__((ext_vector_type(4))) u16 ushort4_t;

// ---------- scalar conversion helpers --------------------------------------
__device__ __forceinline__ float bf2f(u16 u) {
    u32 x = ((u32)u) << 16;
    return __uint_as_float(x);
}
__device__ __forceinline__ u16 f2bf(float f) {  // round-to-nearest-even
    u32 x = __float_as_uint(f);
    x += 0x7FFFu + ((x >> 16) & 1u);
    return (u16)(x >> 16);
}
__device__ __forceinline__ u16 f2h(float f) {
    union { _Float16 h; u16 u; } c; c.h = (_Float16)f;
    return c.u;
}

// ---------- async global->LDS (16B per lane, wave-uniform base) ------------
using as1_cv = __attribute__((address_space(1))) const void;
using as3_v  = __attribute__((address_space(3))) void;
__device__ __forceinline__ void gld16(const void* g, void* l) {
    __builtin_amdgcn_global_load_lds((as1_cv*)g, (as3_v*)l, 16, 0, 0);
}

// ---------- fp32 -> bf16 convert (4 elems/thread) --------------------------
__global__ void cvt_f32_bf16(const float* __restrict__ in, u16* __restrict__ out, int n4) {
    int i = blockIdx.x * 256 + threadIdx.x;
    if (i >= n4) return;
    float4 v = ((const float4*)in)[i];
    ushort4_t o;
    o[0] = f2bf(v.x); o[1] = f2bf(v.y); o[2] = f2bf(v.z); o[3] = f2bf(v.w);
    ((ushort4_t*)out)[i] = o;
}

// ---------- GEMM: C[M,N] = A[M,K] * B[N,K]^T, bf16 inputs ------------------
// OUT_MODE: 0 = bf16 row-major, 1 = f32 row-major, 2 = f16 TRANSPOSED (Ct[N,M])
template <int OUT_MODE>
__global__ __launch_bounds__(256) void gemm_bt(
    const u16* __restrict__ A, const u16* __restrict__ B,
    u16* __restrict__ Cb, float* __restrict__ Cf,
    int M, int N, int K)
{
    __shared__ __align__(16) u16 As[128 * 32];
    __shared__ __align__(16) u16 Bs[128 * 32];
    const int t    = threadIdx.x;
    const int lane = t & 63;
    const int w    = t >> 6;
    const int wm   = w & 1;
    const int wn   = w >> 1;
    const int bx   = blockIdx.x;
    const int by   = blockIdx.y;

    const int r  = t >> 2;
    const int c8 = (t & 3) * 8;
    const u16* gA0 = A + (size_t)(by * 128 + r) * K + c8;
    const u16* gA1 = gA0 + (size_t)64 * K;
    const u16* gB0 = B + (size_t)(bx * 128 + r) * K + c8;
    const u16* gB1 = gB0 + (size_t)64 * K;
    u16* lA0 = &As[t * 8];
    u16* lA1 = &As[2048 + t * 8];
    u16* lB0 = &Bs[t * 8];
    u16* lB1 = &Bs[2048 + t * 8];

    f32x4 acc[4][4] = {};

    const int arow = wm * 64 + (lane & 15);
    const int brow = wn * 64 + (lane & 15);
    const int koff = (lane >> 4) * 8;

    for (int kt = 0; kt < K; kt += 32) {
        gld16(gA0 + kt, lA0);
        gld16(gA1 + kt, lA1);
        gld16(gB0 + kt, lB0);
        gld16(gB1 + kt, lB1);
        __syncthreads();
        short8 af[4], bf[4];
#pragma unroll
        for (int i = 0; i < 4; i++)
            af[i] = *(const short8*)&As[(arow + i * 16) * 32 + koff];
#pragma unroll
        for (int i = 0; i < 4; i++)
            bf[i] = *(const short8*)&Bs[(brow + i * 16) * 32 + koff];
#pragma unroll
        for (int mi = 0; mi < 4; mi++)
#pragma unroll
            for (int ni = 0; ni < 4; ni++)
                acc[mi][ni] = __builtin_amdgcn_mfma_f32_16x16x32_bf16(
                    af[mi], bf[ni], acc[mi][ni], 0, 0, 0);
        __syncthreads();
    }

    const int row0 = by * 128 + wm * 64 + (lane >> 4) * 4;
    const int col0 = bx * 128 + wn * 64 + (lane & 15);
#pragma unroll
    for (int mi = 0; mi < 4; mi++) {
#pragma unroll
        for (int ni = 0; ni < 4; ni++) {
            if (OUT_MODE == 2) {
                ushort4_t o;
#pragma unroll
                for (int rr = 0; rr < 4; rr++) o[rr] = f2h(acc[mi][ni][rr]);
                int col = col0 + ni * 16;
                *(ushort4_t*)&Cb[(size_t)col * M + row0 + mi * 16] = o;
            } else {
#pragma unroll
                for (int rr = 0; rr < 4; rr++) {
                    int row = row0 + mi * 16 + rr;
                    int col = col0 + ni * 16;
                    float v = acc[mi][ni][rr];
                    if (OUT_MODE == 1) Cf[(size_t)row * N + col] = v;
                    else               Cb[(size_t)row * N + col] = f2bf(v);
                }
            }
        }
    }
}

// ---------- RoPE in-place on bf16 [B*S, H*128], optional pre-scale ---------
__global__ void rope_k(u16* __restrict__ x, int hshift, float scale) {
    int idx = blockIdx.x * 256 + threadIdx.x;
    int i   = idx & 63;
    int hm  = (1 << (hshift - 6)) - 1;
    int h   = (idx >> 6) & hm;
    int row = idx >> hshift;
    int s   = row & 2047;
    int stride = (hm + 1) * 128;
    size_t base = (size_t)row * stride + h * 128 + i;
    float th = (float)s * powf(10000.0f, -(float)i / 64.0f);
    float cs = cosf(th) * scale, sn = sinf(th) * scale;
    float x1 = bf2f(x[base]), x2 = bf2f(x[base + 64]);
    x[base]      = f2bf(x1 * cs - x2 * sn);
    x[base + 64] = f2bf(x2 * cs + x1 * sn);
}

// ---------- causal flash attention v3 --------------------------------------
// grid (16, NH, B); 4 waves/block; block = 128 q rows, wave = 32 q (2 subtiles).
// 64-key steps, double-buffered LDS, raw s_barrier + explicit vmcnt so the
// next step's global_load_lds stays in flight across the compute phase.
// QK^T: S^T = Kperm * Q^T (bf16 x32 MFMA); PV: O^T = V^T * P^T (f16 x32 MFMA,
// P packed via v_cvt_pkrtz). V^T LDS chunks XOR-swizzled on the GLOBAL side
// (lane-linear LDS dest) for conflict-free reads.
__global__ __launch_bounds__(256) void flash_attn(
    const u16* __restrict__ qb, const u16* __restrict__ kb,
    const u16* __restrict__ vt, u16* __restrict__ ob)
{
    __shared__ __align__(16) u16 Ks[2 * 8192];
    __shared__ __align__(16) u16 Vs[2 * 8192];
    const int t    = threadIdx.x;
    const int lane = t & 63;
    const int w    = t >> 6;
    const int col  = lane & 15;
    const int g    = lane >> 4;
    const int qt   = 15 - (int)blockIdx.x;   // long tiles first
    const int qh   = blockIdx.y;
    const int b    = blockIdx.z;
    const int kvh  = qh >> 2;
    const int Q0   = qt * 128;
    const int qw   = Q0 + w * 32;

    // Q fragments (B-operand): Q[q][c*32 + g*8 + j]  (Q pre-scaled by 1/sqrt(128))
    short8 qf[2][4];
#pragma unroll
    for (int sub = 0; sub < 2; sub++) {
        const u16* qrow = qb + ((size_t)(b * 2048 + qw + sub * 16 + col)) * 4096 + qh * 128;
#pragma unroll
        for (int c = 0; c < 4; c++)
            qf[sub][c] = *(const short8*)(qrow + c * 32 + g * 8);
    }

    const u16* kbase = kb + ((size_t)b * 2048) * 1024 + kvh * 128;
    const u16* vbase = vt + ((size_t)kvh * 128) * 4096 + (size_t)b * 2048;

    // staging addresses (lane-linear LDS dest)
    const int key_s = t >> 4;
    const int swk   = (key_s & 3) ^ ((key_s & 8) >> 1);
    const u16* gk = kbase + (size_t)key_s * 1024 + ((t & 15) ^ swk) * 8;
    const int vd = t >> 3;
    const u16* gv = vbase + (size_t)vd * 4096 + ((t & 7) ^ (vd & 7)) * 8;
    u16* lk = Ks + t * 8;
    u16* lv = Vs + t * 8;

    // K read offsets (u16 idx in buffer): key = h*32 + (col>>2)*8 + kk*4 + (col&3)
    int kofs[4][4];
#pragma unroll
    for (int hk = 0; hk < 4; hk++) {
        int h = hk >> 1, kk = hk & 1;
        int key = h * 32 + ((col >> 2) * 8) + kk * 4 + (col & 3);
        int sw = (key & 3) ^ ((key & 8) >> 1);
#pragma unroll
        for (int c = 0; c < 4; c++)
            kofs[hk][c] = key * 128 + ((c * 4 + g) ^ sw) * 8;
    }
    // V read offsets: slot = (dt*16+col)*8 + ((h*4+g)^(col&7)); + dt*1024 in-loop
    int vofs[2];
#pragma unroll
    for (int h = 0; h < 2; h++)
        vofs[h] = col * 64 + ((h * 4 + g) ^ (col & 7)) * 8;

    float m_run[2] = {-3e38f, -3e38f};
    float l_run[2] = {0.f, 0.f};
    f32x4 ot[2][8] = {};

    const int nsteps = (Q0 + 128) >> 6;   // >= 2
    const int qmaxw  = qw + 31;

    // prologue: stage steps 0 and 1
#pragma unroll
    for (int i = 0; i < 4; i++) {
        gld16(gk + (size_t)(i * 16) * 1024, lk + i * 2048);
        gld16(gv + (size_t)(i * 32) * 4096, lv + i * 2048);
    }
#pragma unroll
    for (int i = 0; i < 4; i++) {
        gld16(gk + (size_t)(64 + i * 16) * 1024, lk + 8192 + i * 2048);
        gld16(gv + (size_t)(i * 32) * 4096 + 64, lv + 8192 + i * 2048);
    }

    for (int s = 0; s < nsteps; s++) {
        const int k0 = s << 6;
        if (s + 1 < nsteps) __builtin_amdgcn_s_waitcnt(0x0F78);  // vmcnt(8)
        else                __builtin_amdgcn_s_waitcnt(0x0F70);  // vmcnt(0)
        __builtin_amdgcn_s_barrier();
        const u16* Kb = Ks + (s & 1) * 8192;
        const u16* Vb = Vs + (s & 1) * 8192;

        if (k0 <= qmaxw) {
            // scores: 32 bf16 MFMAs
            f32x4 sc[2][4] = {};
#pragma unroll
            for (int c = 0; c < 4; c++)
#pragma unroll
                for (int hk = 0; hk < 4; hk++) {
                    short8 kf = *(const short8*)(Kb + kofs[hk][c]);
                    sc[0][hk] = __builtin_amdgcn_mfma_f32_16x16x32_bf16(kf, qf[0][c], sc[0][hk], 0, 0, 0);
                    sc[1][hk] = __builtin_amdgcn_mfma_f32_16x16x32_bf16(kf, qf[1][c], sc[1][hk], 0, 0, 0);
                }
            const bool part = (k0 + 63 > qw);   // wave-uniform
            half8 pf[2][2];
            float alpha[2];
#pragma unroll
            for (int sub = 0; sub < 2; sub++) {
                const int q = qw + sub * 16 + col;
                float sv[16];
#pragma unroll
                for (int hk = 0; hk < 4; hk++) {
                    int h = hk >> 1, kk = hk & 1;
#pragma unroll
                    for (int rr = 0; rr < 4; rr++) {
                        float v = sc[sub][hk][rr];
                        if (part) {
                            int key = k0 + h * 32 + g * 8 + kk * 4 + rr;
                            v = (key <= q) ? v : -3e38f;   // exp underflows to 0
                        }
                        sv[h * 8 + kk * 4 + rr] = v;
                    }
                }
                float tmax = sv[0];
#pragma unroll
                for (int j = 1; j < 16; j++) tmax = fmaxf(tmax, sv[j]);
                tmax = fmaxf(tmax, __shfl_xor(tmax, 16));
                tmax = fmaxf(tmax, __shfl_xor(tmax, 32));
                float m_new = fmaxf(m_run[sub], tmax);
                alpha[sub] = __expf(m_run[sub] - m_new);
                float tsum = 0.f;
                union { half8 v; fp16x2 h2[4]; } P[2];
#pragma unroll
                for (int h = 0; h < 2; h++)
#pragma unroll
                    for (int j2 = 0; j2 < 4; j2++) {
                        float e0 = __expf(sv[h * 8 + j2 * 2]     - m_new);
                        float e1 = __expf(sv[h * 8 + j2 * 2 + 1] - m_new);
                        P[h].h2[j2] = __builtin_amdgcn_cvt_pkrtz(e0, e1);
                        tsum += e0 + e1;
                    }
                tsum += __shfl_xor(tsum, 16);
                tsum += __shfl_xor(tsum, 32);
                l_run[sub] = l_run[sub] * alpha[sub] + tsum;
                m_run[sub] = m_new;
                pf[sub][0] = P[0].v;
                pf[sub][1] = P[1].v;
            }
            if (!__all(alpha[0] == 1.0f && alpha[1] == 1.0f)) {
#pragma unroll
                for (int sub = 0; sub < 2; sub++)
#pragma unroll
                    for (int dt = 0; dt < 8; dt++)
#pragma unroll
                        for (int rr = 0; rr < 4; rr++) ot[sub][dt][rr] *= alpha[sub];
            }
            // PV: 32 f16 MFMAs
#pragma unroll
            for (int dt = 0; dt < 8; dt++)
#pragma unroll
                for (int h = 0; h < 2; h++) {
                    half8 vf = *(const half8*)(Vb + vofs[h] + dt * 1024);
                    ot[0][dt] = __builtin_amdgcn_mfma_f32_16x16x32_f16(vf, pf[0][h], ot[0][dt], 0, 0, 0);
                    ot[1][dt] = __builtin_amdgcn_mfma_f32_16x16x32_f16(vf, pf[1][h], ot[1][dt], 0, 0, 0);
                }
        }
        __builtin_amdgcn_s_barrier();
        if (s + 2 < nsteps) {
            const int kn = (s + 2) << 6;
            u16* lkd = lk + (s & 1) * 8192;
            u16* lvd = lv + (s & 1) * 8192;
#pragma unroll
            for (int i = 0; i < 4; i++) {
                gld16(gk + (size_t)(kn + i * 16) * 1024, lkd + i * 2048);
                gld16(gv + (size_t)(i * 32) * 4096 + kn, lvd + i * 2048);
            }
        }
    }

    // epilogue: O^T C-layout: dim = dt*16 + g*4 + rr, query = col
#pragma unroll
    for (int sub = 0; sub < 2; sub++) {
        float inv = 1.0f / l_run[sub];
        u16* orow = ob + ((size_t)(b * 2048 + qw + sub * 16 + col)) * 4096 + qh * 128;
#pragma unroll
        for (int dt = 0; dt < 8; dt++) {
            ushort4_t o;
#pragma unroll
            for (int rr = 0; rr < 4; rr++) o[rr] = f2bf(ot[sub][dt][rr] * inv);
            *(ushort4_t*)(orow + dt * 16 + g * 4) = o;
        }
    }
}

// ---------------------------------------------------------------------------
extern "C" void kernel_launch(void* const* d_in, const int* in_sizes, int n_in,
                              void* d_out, int out_size, void* d_ws, size_t ws_size,
                              hipStream_t stream) {
    const float* hs = (const float*)d_in[0];
    const float* Wq = (const float*)d_in[1];
    const float* Wk = (const float*)d_in[2];
    const float* Wv = (const float*)d_in[3];
    const float* Wo = (const float*)d_in[4];
    float* out = (float*)d_out;

    char* ws = (char*)d_ws;
    u16* hsb = (u16*)(ws + 0);
    u16* Wqb = (u16*)(ws + 33554432);
    u16* Wkb = (u16*)(ws + 67108864);
    u16* Wvb = (u16*)(ws + 75497472);
    u16* Wob = (u16*)(ws + 83886080);
    u16* qb  = (u16*)(ws + 117440512);
    u16* kbf = (u16*)(ws + 150994944);
    u16* vtb = (u16*)(ws + 159383552);   // [1024,4096] f16, V transposed
    u16* ab  = hsb;                      // alias: hs dead after QKV GEMMs

    cvt_f32_bf16<<<16384, 256, 0, stream>>>(hs, hsb, 4194304);
    cvt_f32_bf16<<<16384, 256, 0, stream>>>(Wq, Wqb, 4194304);
    cvt_f32_bf16<<<4096,  256, 0, stream>>>(Wk, Wkb, 1048576);
    cvt_f32_bf16<<<4096,  256, 0, stream>>>(Wv, Wvb, 1048576);
    cvt_f32_bf16<<<16384, 256, 0, stream>>>(Wo, Wob, 4194304);

    gemm_bt<0><<<dim3(32, 32), 256, 0, stream>>>(hsb, Wqb, qb,  nullptr, 4096, 4096, 4096);
    gemm_bt<0><<<dim3(8, 32),  256, 0, stream>>>(hsb, Wkb, kbf, nullptr, 4096, 1024, 4096);
    gemm_bt<2><<<dim3(8, 32),  256, 0, stream>>>(hsb, Wvb, vtb, nullptr, 4096, 1024, 4096);

    rope_k<<<32768, 256, 0, stream>>>(qb,  11, 0.08838834764831845f);
    rope_k<<<8192,  256, 0, stream>>>(kbf, 9, 1.0f);

    flash_attn<<<dim3(16, 32, 2), 256, 0, stream>>>(qb, kbf, vtb, ab);

    gemm_bt<1><<<dim3(32, 32), 256, 0, stream>>>(ab, Wob, nullptr, out, 4096, 4096, 4096);
}